// Round 1
// baseline (388.190 us; speedup 1.0000x reference)
//
#include <hip/hip_runtime.h>
#include <math.h>

#define N_NODES 50000
#define N_EDGES 800000
#define D 128

// ---------------- CSR build ----------------

__global__ __launch_bounds__(256) void zero_cnt(int* __restrict__ cnt) {
    int i = blockIdx.x * 256 + threadIdx.x;
    if (i < N_NODES) cnt[i] = 0;
}

__global__ __launch_bounds__(256) void count_deg(const int* __restrict__ ei, int* __restrict__ cnt) {
    int e = blockIdx.x * 256 + threadIdx.x;
    if (e >= N_EDGES) return;
    int dst = ei[N_EDGES + e];
    atomicAdd(&cnt[dst], 1);
}

// per-chunk (512 elems) reduction
__global__ __launch_bounds__(256) void scan_reduce(const int* __restrict__ cnt, int* __restrict__ bsums) {
    int base = blockIdx.x * 512;
    int t = threadIdx.x;
    int i0 = base + 2 * t, i1 = i0 + 1;
    int s = 0;
    if (i0 < N_NODES) s += cnt[i0];
    if (i1 < N_NODES) s += cnt[i1];
    __shared__ int sm[256];
    sm[t] = s; __syncthreads();
    for (int o = 128; o > 0; o >>= 1) {
        if (t < o) sm[t] += sm[t + o];
        __syncthreads();
    }
    if (t == 0) bsums[blockIdx.x] = sm[0];
}

// single-block exclusive scan of the 98 block sums; also writes row_start[N]
__global__ __launch_bounds__(128) void scan_blocksums(const int* __restrict__ bsums,
                                                      int* __restrict__ boffs,
                                                      int* __restrict__ row_start, int nb) {
    __shared__ int sm[128];
    int t = threadIdx.x;
    int v = (t < nb) ? bsums[t] : 0;
    sm[t] = v; __syncthreads();
    for (int o = 1; o < 128; o <<= 1) {
        int add = (t >= o) ? sm[t - o] : 0;
        __syncthreads();
        sm[t] += add;
        __syncthreads();
    }
    if (t < nb) boffs[t] = sm[t] - v;          // exclusive prefix
    if (t == nb - 1) row_start[N_NODES] = sm[t]; // total == N_EDGES
}

// per-chunk exclusive scan + global offset; also derives cursor and dinv
__global__ __launch_bounds__(256) void scan_final(const int* __restrict__ cnt,
                                                  const int* __restrict__ boffs,
                                                  int* __restrict__ row_start,
                                                  int* __restrict__ cursor,
                                                  float* __restrict__ dinv) {
    int base = blockIdx.x * 512;
    int t = threadIdx.x;
    int i0 = base + 2 * t, i1 = i0 + 1;
    int a = (i0 < N_NODES) ? cnt[i0] : 0;
    int b = (i1 < N_NODES) ? cnt[i1] : 0;
    int psum = a + b;
    __shared__ int sm[256];
    sm[t] = psum; __syncthreads();
    for (int o = 1; o < 256; o <<= 1) {
        int add = (t >= o) ? sm[t - o] : 0;
        __syncthreads();
        sm[t] += add;
        __syncthreads();
    }
    int excl = sm[t] - psum + boffs[blockIdx.x];
    if (i0 < N_NODES) {
        row_start[i0] = excl;
        cursor[i0] = excl;
        dinv[i0] = rsqrtf((float)(a + 1));   // deg includes self-loop
    }
    if (i1 < N_NODES) {
        row_start[i1] = excl + a;
        cursor[i1] = excl + a;
        dinv[i1] = rsqrtf((float)(b + 1));
    }
}

__global__ __launch_bounds__(256) void fill_csr(const int* __restrict__ ei,
                                                int* __restrict__ cursor,
                                                int* __restrict__ ssrc) {
    int e = blockIdx.x * 256 + threadIdx.x;
    if (e >= N_EDGES) return;
    int src = ei[e];
    int dst = ei[N_EDGES + e];
    int p = atomicAdd(&cursor[dst], 1);
    ssrc[p] = src;
}

// ---------------- dense transform h = x @ W ----------------
// W transposed into LDS (padded stride 132 so float4 reads are ~conflict-free),
// 16 rows per iteration register-tiled -> W LDS traffic amortized, FMA-bound.

__global__ __launch_bounds__(128) void gemm_xw(const float* __restrict__ x,
                                               const float* __restrict__ W,
                                               float* __restrict__ h) {
    __shared__ float wt[128 * 132];   // wt[j*132 + k] = W[k][j]
    __shared__ float xr[16][128];
    int t = threadIdx.x;              // output column j
    for (int idx = t; idx < 128 * 128; idx += 128) {
        int k = idx >> 7, j = idx & 127;
        wt[j * 132 + k] = W[idx];
    }
    __syncthreads();
    for (int base = blockIdx.x * 16; base < N_NODES; base += gridDim.x * 16) {
        #pragma unroll
        for (int r = 0; r < 16; ++r) {
            int row = base + r;
            if (row < N_NODES) xr[r][t] = x[row * 128 + t];
        }
        __syncthreads();
        float acc[16];
        #pragma unroll
        for (int r = 0; r < 16; ++r) acc[r] = 0.f;
        const float4* wv4 = (const float4*)&wt[t * 132];
        #pragma unroll 8
        for (int k4 = 0; k4 < 32; ++k4) {
            float4 w4 = wv4[k4];
            #pragma unroll
            for (int r = 0; r < 16; ++r) {
                float4 x4 = *(const float4*)&xr[r][k4 * 4];
                acc[r] += w4.x * x4.x + w4.y * x4.y + w4.z * x4.z + w4.w * x4.w;
            }
        }
        #pragma unroll
        for (int r = 0; r < 16; ++r) {
            int row = base + r;
            if (row < N_NODES) h[row * 128 + t] = acc[r];
        }
        __syncthreads();
    }
}

// ---------------- gather-aggregate ----------------
// out[i] = dinv[i] * sum_e dinv[src_e] * h[src_e] + dinv[i]^2 * h[i] + b

__global__ __launch_bounds__(128) void aggregate(const float* __restrict__ h,
                                                 const int* __restrict__ row_start,
                                                 const int* __restrict__ ssrc,
                                                 const float* __restrict__ dinv,
                                                 const float* __restrict__ bias,
                                                 float* __restrict__ out) {
    int i = blockIdx.x;
    int d = threadIdx.x;
    int s = row_start[i];
    int t = row_start[i + 1];
    float acc = 0.f;
    for (int e = s; e < t; ++e) {
        int src = ssrc[e];
        acc += dinv[src] * h[src * 128 + d];
    }
    float di = dinv[i];
    out[i * 128 + d] = di * acc + di * di * h[i * 128 + d] + bias[d];
}

// ---------------- launch ----------------

extern "C" void kernel_launch(void* const* d_in, const int* in_sizes, int n_in,
                              void* d_out, int out_size, void* d_ws, size_t ws_size,
                              hipStream_t stream) {
    const float* x  = (const float*)d_in[0];
    const int*   ei = (const int*)d_in[1];     // [2, E] int (dtype per harness contract)
    const float* W  = (const float*)d_in[2];
    const float* b  = (const float*)d_in[3];
    float* out = (float*)d_out;

    char* ws = (char*)d_ws;
    float* h         = (float*)(ws + 0);           // 25,600,000 B
    int*   cnt       = (int*)  (ws + 25600000);    //    200,000 B
    int*   row_start = (int*)  (ws + 25800000);    //    200,004 B
    int*   cursor    = (int*)  (ws + 26000208);    //    200,000 B
    float* dinv      = (float*)(ws + 26200208);    //    200,000 B
    int*   ssrc      = (int*)  (ws + 26400208);    //  3,200,000 B
    int*   bsums     = (int*)  (ws + 29600208);    //        392 B
    int*   boffs     = (int*)  (ws + 29600608);    //        392 B

    const int nb = (N_NODES + 511) / 512;          // 98 scan chunks

    hipLaunchKernelGGL(zero_cnt,       dim3((N_NODES + 255) / 256), dim3(256), 0, stream, cnt);
    hipLaunchKernelGGL(count_deg,      dim3((N_EDGES + 255) / 256), dim3(256), 0, stream, ei, cnt);
    hipLaunchKernelGGL(scan_reduce,    dim3(nb),  dim3(256), 0, stream, cnt, bsums);
    hipLaunchKernelGGL(scan_blocksums, dim3(1),   dim3(128), 0, stream, bsums, boffs, row_start, nb);
    hipLaunchKernelGGL(scan_final,     dim3(nb),  dim3(256), 0, stream, cnt, boffs, row_start, cursor, dinv);
    hipLaunchKernelGGL(fill_csr,       dim3((N_EDGES + 255) / 256), dim3(256), 0, stream, ei, cursor, ssrc);
    hipLaunchKernelGGL(gemm_xw,        dim3(512), dim3(128), 0, stream, x, W, h);
    hipLaunchKernelGGL(aggregate,      dim3(N_NODES), dim3(128), 0, stream, h, row_start, ssrc, dinv, b, out);
}

// Round 3
// 247.040 us; speedup vs baseline: 1.5714x; 1.5714x over previous
//
#include <hip/hip_runtime.h>
#include <math.h>

#define N_NODES 50000
#define N_EDGES 800000
#define D 128

typedef short bf16x8 __attribute__((ext_vector_type(8)));
typedef float f32x4 __attribute__((ext_vector_type(4)));

static __device__ __forceinline__ unsigned short f2bf_rn(float f) {
    unsigned u = __float_as_uint(f);
    unsigned r = (u + 0x7FFF + ((u >> 16) & 1)) >> 16;
    return (unsigned short)r;
}
static __device__ __forceinline__ float bf2f(unsigned short h) {
    return __uint_as_float(((unsigned)h) << 16);
}

// ---------------- CSR build ----------------

__global__ __launch_bounds__(256) void zero_cnt(int* __restrict__ cnt) {
    int i = blockIdx.x * 256 + threadIdx.x;
    if (i < N_NODES) cnt[i] = 0;
}

__global__ __launch_bounds__(256) void count_deg(const int* __restrict__ ei, int* __restrict__ cnt) {
    int e = blockIdx.x * 256 + threadIdx.x;
    if (e >= N_EDGES) return;
    int dst = ei[N_EDGES + e];
    atomicAdd(&cnt[dst], 1);
}

__global__ __launch_bounds__(256) void scan_reduce(const int* __restrict__ cnt, int* __restrict__ bsums) {
    int base = blockIdx.x * 512;
    int t = threadIdx.x;
    int i0 = base + 2 * t, i1 = i0 + 1;
    int s = 0;
    if (i0 < N_NODES) s += cnt[i0];
    if (i1 < N_NODES) s += cnt[i1];
    __shared__ int sm[256];
    sm[t] = s; __syncthreads();
    for (int o = 128; o > 0; o >>= 1) {
        if (t < o) sm[t] += sm[t + o];
        __syncthreads();
    }
    if (t == 0) bsums[blockIdx.x] = sm[0];
}

__global__ __launch_bounds__(128) void scan_blocksums(const int* __restrict__ bsums,
                                                      int* __restrict__ boffs,
                                                      int* __restrict__ row_start, int nb) {
    __shared__ int sm[128];
    int t = threadIdx.x;
    int v = (t < nb) ? bsums[t] : 0;
    sm[t] = v; __syncthreads();
    for (int o = 1; o < 128; o <<= 1) {
        int add = (t >= o) ? sm[t - o] : 0;
        __syncthreads();
        sm[t] += add;
        __syncthreads();
    }
    if (t < nb) boffs[t] = sm[t] - v;
    if (t == nb - 1) row_start[N_NODES] = sm[t];
}

__global__ __launch_bounds__(256) void scan_final(const int* __restrict__ cnt,
                                                  const int* __restrict__ boffs,
                                                  int* __restrict__ row_start,
                                                  int* __restrict__ cursor,
                                                  float* __restrict__ dinv) {
    int base = blockIdx.x * 512;
    int t = threadIdx.x;
    int i0 = base + 2 * t, i1 = i0 + 1;
    int a = (i0 < N_NODES) ? cnt[i0] : 0;
    int b = (i1 < N_NODES) ? cnt[i1] : 0;
    int psum = a + b;
    __shared__ int sm[256];
    sm[t] = psum; __syncthreads();
    for (int o = 1; o < 256; o <<= 1) {
        int add = (t >= o) ? sm[t - o] : 0;
        __syncthreads();
        sm[t] += add;
        __syncthreads();
    }
    int excl = sm[t] - psum + boffs[blockIdx.x];
    if (i0 < N_NODES) {
        row_start[i0] = excl;
        cursor[i0] = excl;
        dinv[i0] = rsqrtf((float)(a + 1));
    }
    if (i1 < N_NODES) {
        row_start[i1] = excl + a;
        cursor[i1] = excl + a;
        dinv[i1] = rsqrtf((float)(b + 1));
    }
}

__global__ __launch_bounds__(256) void fill_csr(const int* __restrict__ ei,
                                                int* __restrict__ cursor,
                                                int* __restrict__ ssrc) {
    int e = blockIdx.x * 256 + threadIdx.x;
    if (e >= N_EDGES) return;
    int src = ei[e];
    int dst = ei[N_EDGES + e];
    int p = atomicAdd(&cursor[dst], 1);
    ssrc[p] = src;
}

// ---------------- W fragment prep (bf16 hi/lo, MFMA B-layout) ----------------
// Fragment for mfma_f32_16x16x32_bf16 B operand: lane l holds
// B[k = kstep*32 + (l>>4)*8 + e][c = ctile*16 + (l&15)], e = 0..7.
// Packed: wfrag[((kstep*8 + ctile)*64 + lane)*8 + e]

__global__ __launch_bounds__(256) void prep_w(const float* __restrict__ W,
                                              unsigned short* __restrict__ wH,
                                              unsigned short* __restrict__ wL) {
    int tid = blockIdx.x * 256 + threadIdx.x;   // 0..2047
    if (tid >= 2048) return;
    int kstep = tid >> 9;
    int ct = (tid >> 6) & 7;
    int lane = tid & 63;
    int kbase = kstep * 32 + ((lane >> 4) << 3);
    int c = ct * 16 + (lane & 15);
    #pragma unroll
    for (int e = 0; e < 8; ++e) {
        float v = W[(kbase + e) * 128 + c];
        unsigned short hb = f2bf_rn(v);
        float res = v - bf2f(hb);
        unsigned short lb = f2bf_rn(res);
        wH[tid * 8 + e] = hb;
        wL[tid * 8 + e] = lb;
    }
}

// ---------------- dense transform h = x @ W via bf16x3 MFMA ----------------
// Block = 4 waves, 64 rows. Wave w: rows [base + w*16, +16), all 128 cols.

__global__ __launch_bounds__(256) void gemm_xw_mfma(const float* __restrict__ x,
                                                    const unsigned short* __restrict__ wH,
                                                    const unsigned short* __restrict__ wL,
                                                    float* __restrict__ h) {
    int wave = threadIdx.x >> 6;
    int lane = threadIdx.x & 63;
    int rowbase = blockIdx.x * 64 + wave * 16;

    f32x4 acc[8];
    #pragma unroll
    for (int ct = 0; ct < 8; ++ct) acc[ct] = (f32x4)(0.f);

    int arow = rowbase + (lane & 15);
    if (arow >= N_NODES) arow = N_NODES - 1;
    const float* xrow = x + arow * 128 + ((lane >> 4) << 3);

    #pragma unroll
    for (int kstep = 0; kstep < 4; ++kstep) {
        float4 a0 = *(const float4*)(xrow + kstep * 32);
        float4 a1 = *(const float4*)(xrow + kstep * 32 + 4);
        float av[8] = {a0.x, a0.y, a0.z, a0.w, a1.x, a1.y, a1.z, a1.w};
        bf16x8 ah, al;
        #pragma unroll
        for (int e = 0; e < 8; ++e) {
            unsigned short hb = f2bf_rn(av[e]);
            float res = av[e] - bf2f(hb);
            ah[e] = (short)hb;
            al[e] = (short)f2bf_rn(res);
        }
        const bf16x8* bh = (const bf16x8*)(wH + (size_t)(kstep * 8) * 64 * 8 + lane * 8);
        const bf16x8* bl = (const bf16x8*)(wL + (size_t)(kstep * 8) * 64 * 8 + lane * 8);
        #pragma unroll
        for (int ct = 0; ct < 8; ++ct) {
            bf16x8 bhv = bh[ct * 64];
            bf16x8 blv = bl[ct * 64];
            acc[ct] = __builtin_amdgcn_mfma_f32_16x16x32_bf16(ah, bhv, acc[ct], 0, 0, 0);
            acc[ct] = __builtin_amdgcn_mfma_f32_16x16x32_bf16(ah, blv, acc[ct], 0, 0, 0);
            acc[ct] = __builtin_amdgcn_mfma_f32_16x16x32_bf16(al, bhv, acc[ct], 0, 0, 0);
        }
    }

    int rbase = rowbase + ((lane >> 4) << 2);
    int col = lane & 15;
    #pragma unroll
    for (int ct = 0; ct < 8; ++ct) {
        #pragma unroll
        for (int i = 0; i < 4; ++i) {
            int row = rbase + i;
            if (row < N_NODES) h[row * 128 + ct * 16 + col] = acc[ct][i];
        }
    }
}

// ---------------- gather-aggregate (wave per node) ----------------
// out[i] = dinv[i] * sum_e dinv[src]*h[src] + dinv[i]^2*h[i] + b

__global__ __launch_bounds__(256) void aggregate(const float* __restrict__ h,
                                                 const int* __restrict__ row_start,
                                                 const int* __restrict__ ssrc,
                                                 const float* __restrict__ dinv,
                                                 const float* __restrict__ bias,
                                                 float* __restrict__ out) {
    int node = blockIdx.x * 4 + (threadIdx.x >> 6);
    int lane = threadIdx.x & 63;
    if (node >= N_NODES) return;
    int s = row_start[node];
    int t = row_start[node + 1];
    float acc0 = 0.f, acc1 = 0.f;
    for (int base = s; base < t; base += 64) {
        int c = t - base;
        if (c > 64) c = 64;
        int li = base + (lane < c ? lane : c - 1);
        int idx = ssrc[li];
        float dv = dinv[idx];
        int j = 0;
        for (; j + 4 <= c; j += 4) {
            int s0 = __shfl(idx, j), s1 = __shfl(idx, j + 1);
            int s2 = __shfl(idx, j + 2), s3 = __shfl(idx, j + 3);
            float d0 = __shfl(dv, j), d1 = __shfl(dv, j + 1);
            float d2 = __shfl(dv, j + 2), d3 = __shfl(dv, j + 3);
            const float* p0 = h + (size_t)s0 * 128 + lane;
            const float* p1 = h + (size_t)s1 * 128 + lane;
            const float* p2 = h + (size_t)s2 * 128 + lane;
            const float* p3 = h + (size_t)s3 * 128 + lane;
            float v00 = p0[0], v01 = p0[64];
            float v10 = p1[0], v11 = p1[64];
            float v20 = p2[0], v21 = p2[64];
            float v30 = p3[0], v31 = p3[64];
            acc0 += d0 * v00 + d1 * v10 + d2 * v20 + d3 * v30;
            acc1 += d0 * v01 + d1 * v11 + d2 * v21 + d3 * v31;
        }
        for (; j < c; ++j) {
            int sj = __shfl(idx, j);
            float dj = __shfl(dv, j);
            acc0 += dj * h[(size_t)sj * 128 + lane];
            acc1 += dj * h[(size_t)sj * 128 + 64 + lane];
        }
    }
    float di = dinv[node];
    out[(size_t)node * 128 + lane] = di * acc0 + di * di * h[(size_t)node * 128 + lane] + bias[lane];
    out[(size_t)node * 128 + 64 + lane] = di * acc1 + di * di * h[(size_t)node * 128 + 64 + lane] + bias[64 + lane];
}

// ---------------- launch ----------------

extern "C" void kernel_launch(void* const* d_in, const int* in_sizes, int n_in,
                              void* d_out, int out_size, void* d_ws, size_t ws_size,
                              hipStream_t stream) {
    const float* x  = (const float*)d_in[0];
    const int*   ei = (const int*)d_in[1];
    const float* W  = (const float*)d_in[2];
    const float* b  = (const float*)d_in[3];
    float* out = (float*)d_out;

    char* ws = (char*)d_ws;
    float* h             = (float*)(ws + 0);            // 25,600,000
    int*   cnt           = (int*)  (ws + 25600000);     //    200,000
    int*   row_start     = (int*)  (ws + 25800000);     //    200,004
    int*   cursor        = (int*)  (ws + 26000208);     //    200,000
    float* dinv          = (float*)(ws + 26200208);     //    200,000
    int*   ssrc          = (int*)  (ws + 26400208);     //  3,200,000
    int*   bsums         = (int*)  (ws + 29600208);     //        392
    int*   boffs         = (int*)  (ws + 29600608);     //        392
    unsigned short* wH   = (unsigned short*)(ws + 29601024); // 32,768 (16B aligned)
    unsigned short* wL   = (unsigned short*)(ws + 29633792); // 32,768

    const int nb = (N_NODES + 511) / 512;

    hipLaunchKernelGGL(zero_cnt,       dim3((N_NODES + 255) / 256), dim3(256), 0, stream, cnt);
    hipLaunchKernelGGL(count_deg,      dim3((N_EDGES + 255) / 256), dim3(256), 0, stream, ei, cnt);
    hipLaunchKernelGGL(scan_reduce,    dim3(nb),  dim3(256), 0, stream, cnt, bsums);
    hipLaunchKernelGGL(scan_blocksums, dim3(1),   dim3(128), 0, stream, bsums, boffs, row_start, nb);
    hipLaunchKernelGGL(scan_final,     dim3(nb),  dim3(256), 0, stream, cnt, boffs, row_start, cursor, dinv);
    hipLaunchKernelGGL(fill_csr,       dim3((N_EDGES + 255) / 256), dim3(256), 0, stream, ei, cursor, ssrc);
    hipLaunchKernelGGL(prep_w,         dim3(8),   dim3(256), 0, stream, W, wH, wL);
    hipLaunchKernelGGL(gemm_xw_mfma,   dim3((N_NODES + 63) / 64), dim3(256), 0, stream, x, wH, wL, h);
    hipLaunchKernelGGL(aggregate,      dim3((N_NODES + 3) / 4), dim3(256), 0, stream, h, row_start, ssrc, dinv, b, out);
}